// Round 2
// baseline (27130.276 us; speedup 1.0000x reference)
//
#include <hip/hip_runtime.h>

#define N_  1024
#define T_  512
#define B_  128
#define NI_ 6
#define NO_ 2
#define NS_ 0.13416407864998738f   // sqrt(2/alpha)*sigma = sqrt(20)*0.03
#define ALPHA_ 0.1f
#define GAMMA_ 0.1f

#define NGROUP 8        // column groups (16 cols each) -- barrier scope
#define CPG    16       // cols per group
#define RPB    32       // rows per block
#define SPAD   1028     // sLDS row stride (pad breaks bank conflicts)
#define SBSTR  (N_ * CPG)   // floats per group state buffer
#define PWI(w,r,c) (((w) * RPB + (r)) * 17 + (c))

// Grid 256 = 8 col-groups x 32 row-blocks. Block 1024 thr = 16 waves.
// g = blockIdx>>5 (col group); within group j=blockIdx&31, R=(j&7)*4+(j>>3):
// XCD x (heuristic blockIdx%8==x) hosts rows [128x,128x+128) for ALL groups ->
// its 512 KB W_rec slice stays L2-resident (no per-step HBM/L3 W traffic).
// Cross-block s goes through L3 via agent-scope atomics (no cache flushes).
__global__ __launch_bounds__(1024) void rnn_kernel(
    const float* __restrict__ u,      // (NI, T, B)
    const float* __restrict__ rn,     // (N, T, B)
    const float* __restrict__ ino,    // (NI, T, B)
    const float* __restrict__ Wrec,   // (N, N)
    const float* __restrict__ Winp,   // (N, NI)
    const float* __restrict__ Wout,   // (NO, N)
    const float* __restrict__ yinit,  // (N,)
    float* __restrict__ out,          // (NO, T, B) pre-zeroed
    unsigned int* __restrict__ arrive,// NGROUP counters (zeroed)
    float* __restrict__ sb)           // 2 x NGROUP x (N*CPG) floats ping-pong
{
    __shared__ float sLDS[CPG * SPAD];      // s_t transposed [c][k], padded (~64.3 KB)
    __shared__ float pw[16 * RPB * 17];     // split-K partials [w][r][c] padded (~34 KB)
    __shared__ float snewLDS[RPB * CPG];    // 2 KB

    const int bid  = blockIdx.x;
    const int g    = bid >> 5;
    const int jj   = bid & 31;
    const int R    = ((jj & 7) << 2) | (jj >> 3);
    const int tid  = threadIdx.x;
    const int wave = tid >> 6;
    const int lane = tid & 63;
    const int rs   = lane >> 4;      // 0..3 (row sub-group: 8 rows each)
    const int c    = lane & 15;      // col within group
    const int col  = g * CPG;

    // ---------------- prologue: s0 = broadcast(yinit) ----------------
    #pragma unroll
    for (int p = 0; p < 16; ++p) {
        const int idx = p * 1024 + tid;          // idx = k*16 + c
        sLDS[(idx & 15) * SPAD + (idx >> 4)] = yinit[idx >> 4];
    }
    if (R == 0) {   // out[:,0,:] = Wout @ yinit (same value for every batch col)
        const float yv = yinit[tid];
        pw[tid]        = Wout[tid] * yv;
        pw[1024 + tid] = Wout[N_ + tid] * yv;
        __syncthreads();
        for (int st = 512; st > 0; st >>= 1) {
            if (tid < st) { pw[tid] += pw[tid + st]; pw[1024 + tid] += pw[1024 + tid + st]; }
            __syncthreads();
        }
        if (tid < CPG)          out[0 * T_ * B_ + col + tid]          = pw[0];
        else if (tid < 2 * CPG) out[1 * T_ * B_ + col + (tid - CPG)]  = pw[1024];
    }
    __syncthreads();

    const int rr = tid >> 4;            // output row (tid<512)
    const int cc = tid & 15;
    const int n  = R * RPB + rr;        // global row for pointwise
    unsigned int target = 0;

    for (int t = 0; t < T_ - 1; ++t) {
        // prefetch pointwise inputs (HBM latency hidden under GEMM)
        float rn_v = 0.f, u_v[NI_], ino_v[NI_];
        if (tid < 512) {
            rn_v = rn[(size_t)n * (T_ * B_) + t * B_ + col + cc];
            #pragma unroll
            for (int q = 0; q < NI_; ++q) {
                u_v[q]   = u[q * (T_ * B_) + t * B_ + col + cc];
                ino_v[q] = ino[q * (T_ * B_) + t * B_ + col + cc];
            }
        }

        // ---- GEMM: wave covers k in [wave*64, +64); lane (rs,c): 8 rows x 1 col
        float acc[8] = {0.f, 0.f, 0.f, 0.f, 0.f, 0.f, 0.f, 0.f};
        const int k0 = wave * 64;
        const float* wbase = Wrec + (size_t)(R * RPB + rs * 8) * N_ + k0;
        const float* sbase = &sLDS[c * SPAD + k0];
        #pragma unroll 4
        for (int kk = 0; kk < 64; kk += 4) {
            const float4 s4 = *(const float4*)&sbase[kk];
            #pragma unroll
            for (int i = 0; i < 8; ++i) {
                const float4 w4 = *(const float4*)&wbase[(size_t)i * N_ + kk];
                acc[i] = fmaf(w4.x, s4.x, acc[i]);
                acc[i] = fmaf(w4.y, s4.y, acc[i]);
                acc[i] = fmaf(w4.z, s4.z, acc[i]);
                acc[i] = fmaf(w4.w, s4.w, acc[i]);
            }
        }
        #pragma unroll
        for (int i = 0; i < 8; ++i)
            pw[PWI(wave, rs * 8 + i, c)] = acc[i];
        __syncthreads();

        // ---- reduce 16-way split-K + pointwise update
        if (tid < 512) {
            float h = 0.f;
            #pragma unroll
            for (int w = 0; w < 16; ++w) h += pw[PWI(w, rr, cc)];
            #pragma unroll
            for (int q = 0; q < NI_; ++q)
                h = fmaf(Winp[n * NI_ + q], fmaf(NS_, ino_v[q], u_v[q]), h);
            const float s_old = sLDS[cc * SPAD + n];
            const float rhs   = -s_old + fmaxf(0.f, h) + NS_ * rn_v
                                - GAMMA_ * s_old * s_old * s_old;
            const float snew  = fmaf(ALPHA_, rhs, s_old);
            // write-through to L3 so other blocks (any XCD) read it coherently
            __hip_atomic_store(&sb[(size_t)(((t + 1) & 1) * NGROUP + g) * SBSTR + n * CPG + cc],
                               snew, __ATOMIC_RELAXED, __HIP_MEMORY_SCOPE_AGENT);
            snewLDS[tid] = snew;
        }
        __syncthreads();

        // ---- out[:, t+1, cols] partial (this block's 32 rows)
        if (tid < NO_ * CPG) {
            const int o = tid >> 4, c2 = tid & 15;
            float p = 0.f;
            #pragma unroll
            for (int r2 = 0; r2 < RPB; ++r2)
                p += Wout[o * N_ + R * RPB + r2] * snewLDS[r2 * CPG + c2];
            atomicAdd(&out[(size_t)o * (T_ * B_) + (t + 1) * B_ + col + c2], p);
        }

        // ---- group barrier (32 blocks). __syncthreads drained vmcnt, so the
        // agent-scope s-stores are already at the coherence point: relaxed is enough.
        target += 32;
        if (t < T_ - 2) {
            if (tid == 0) {
                __hip_atomic_fetch_add(&arrive[g], 1u, __ATOMIC_RELAXED, __HIP_MEMORY_SCOPE_AGENT);
                while (__hip_atomic_load(&arrive[g], __ATOMIC_RELAXED, __HIP_MEMORY_SCOPE_AGENT) < target)
                    __builtin_amdgcn_s_sleep(2);
            }
            __syncthreads();
            // stage s_{t+1}: coherent global -> LDS (transposed)
            const float* src = sb + (size_t)(((t + 1) & 1) * NGROUP + g) * SBSTR;
            #pragma unroll
            for (int p = 0; p < 16; ++p) {
                const int idx = p * 1024 + tid;   // = k*16 + c, coalesced
                sLDS[(idx & 15) * SPAD + (idx >> 4)] =
                    __hip_atomic_load(&src[idx], __ATOMIC_RELAXED, __HIP_MEMORY_SCOPE_AGENT);
            }
            __syncthreads();
        }
    }
}

extern "C" void kernel_launch(void* const* d_in, const int* in_sizes, int n_in,
                              void* d_out, int out_size, void* d_ws, size_t ws_size,
                              hipStream_t stream) {
    const float* u    = (const float*)d_in[0];
    const float* rn   = (const float*)d_in[1];
    const float* ino  = (const float*)d_in[2];
    const float* Wrec = (const float*)d_in[3];
    const float* Winp = (const float*)d_in[4];
    const float* Wout = (const float*)d_in[5];
    const float* yin  = (const float*)d_in[6];
    float* out = (float*)d_out;

    unsigned int* arrive = (unsigned int*)d_ws;                 // 8 counters
    float* sb = (float*)((char*)d_ws + 1024);                   // 1 MB ping-pong

    hipMemsetAsync(d_ws, 0, 1024, stream);
    hipMemsetAsync(d_out, 0, (size_t)out_size * sizeof(float), stream);

    void* args[] = {(void*)&u, (void*)&rn, (void*)&ino, (void*)&Wrec, (void*)&Winp,
                    (void*)&Wout, (void*)&yin, (void*)&out, (void*)&arrive, (void*)&sb};
    hipLaunchCooperativeKernel((void*)rnn_kernel, dim3(256), dim3(1024), args, 0, stream);
}

// Round 3
// 20342.419 us; speedup vs baseline: 1.3337x; 1.3337x over previous
//
#include <hip/hip_runtime.h>

#define N_  1024
#define T_  512
#define B_  128
#define NI_ 6
#define NO_ 2
#define NS_ 0.13416407864998738f   // sqrt(2/alpha)*sigma = sqrt(20)*0.03
#define ALPHA_ 0.1f
#define GAMMA_ 0.1f

#define NG   16     // column groups (8 cols each)
#define CPG  8      // cols per group
#define RPB  64     // rows per block
#define NRB  16     // row-blocks per group
#define SBG  (CPG * N_)          // floats per group slice (8192)
#define SBT  (NG * SBG)          // floats per time buffer (131072)

// system-scope (coherence-point) accesses: bypass L1+L2, coalesced
__device__ __forceinline__ float4 ld_sys(const float4* p) {
    float4 v;
    asm volatile("global_load_dwordx4 %0, %1, off sc0 sc1\n\ts_waitcnt vmcnt(0)"
                 : "=v"(v) : "v"(p) : "memory");
    return v;
}
__device__ __forceinline__ void st_sys(float* p, float v) {
    asm volatile("global_store_dword %0, %1, off sc0 sc1" :: "v"(p), "v"(v) : "memory");
}

// 256 blocks = 16 col-groups x 16 row-blocks; 1024 threads = 16 waves.
// W_rec slice (64 rows x 1024) lives in VGPRs: wave w = k-slice [64w,64w+64),
// lane = row; 16 float4 per thread, loaded once, reused 511 steps.
__global__ __launch_bounds__(1024) void rnn_kernel(
    const float* __restrict__ u,      // (NI, T, B)
    const float* __restrict__ rn,     // (N, T, B)
    const float* __restrict__ ino,    // (NI, T, B)
    const float* __restrict__ Wrec,   // (N, N)
    const float* __restrict__ Winp,   // (N, NI)
    const float* __restrict__ Wout,   // (NO, N)
    const float* __restrict__ yinit,  // (N,)
    float* __restrict__ out,          // (NO, T, B) pre-zeroed
    unsigned int* __restrict__ arrive,// NG counters (zeroed)
    float* __restrict__ sbuf)         // 2 * SBT floats ping-pong
{
    __shared__ float sLDS[CPG * N_];        // s_t slice [c][k]   32 KB
    __shared__ float pw[16 * RPB * CPG];    // split-K partials   32 KB
    __shared__ float rnLDS[RPB * CPG];      // 2 KB
    __shared__ float uLDS[NI_ * CPG];       // 192 B
    __shared__ float inoLDS[NI_ * CPG];     // 192 B

    const int bid  = blockIdx.x;
    const int g    = bid >> 4;            // col group
    const int R    = bid & 15;            // row block
    const int col0 = g * CPG;
    const int r0   = R * RPB;
    const int tid  = threadIdx.x;
    const int wv   = tid >> 6;            // k-slice index (wave)
    const int ln   = tid & 63;            // row within block
    const int k0   = wv * 64;

    // ---- persistent W fragment: W[r0+ln][k0 .. k0+63] ----
    float4 w[16];
    {
        const float* wrow = Wrec + (size_t)(r0 + ln) * N_ + k0;
        #pragma unroll
        for (int kk = 0; kk < 16; ++kk)
            w[kk] = *(const float4*)&wrow[kk * 4];
    }

    // ---- prologue: s0 = broadcast(yinit), out[:,0,:] ----
    #pragma unroll
    for (int i = 0; i < 8; ++i) {
        const int idx = i * 1024 + tid;           // [c][k] flat
        sLDS[idx] = yinit[idx & 1023];
    }
    __syncthreads();
    if (tid < 512) {
        const int c = tid >> 6, r = tid & 63, n = r0 + r;
        const float v = yinit[n];
        #pragma unroll
        for (int o = 0; o < NO_; ++o) {
            float p = Wout[o * N_ + n] * v;
            #pragma unroll
            for (int off = 32; off; off >>= 1) p += __shfl_down(p, off, 64);
            if (r == 0) atomicAdd(&out[(size_t)o * (T_ * B_) + col0 + c], p);
        }
    }

    unsigned int target = 0;

    for (int t = 0; t < T_ - 1; ++t) {
        // ---- prefetch pointwise inputs into registers (overlap with GEMM) ----
        float pf = 0.f;
        if (tid < 512) {                        // rn: 64 n x 8 c, semi-coalesced
            const int pn = tid >> 3, pc = tid & 7;
            pf = rn[(size_t)(r0 + pn) * (T_ * B_) + t * B_ + col0 + pc];
        } else if (tid < 512 + 2 * NI_ * CPG) { // u, ino: 96 values
            const int j = tid - 512;
            const int q = (j >> 3) % NI_, pc = j & 7;
            const float* src = (j < NI_ * CPG) ? u : ino;
            pf = src[q * (T_ * B_) + t * B_ + col0 + pc];
        }

        // ---- GEMM: acc[c] = sum_{k in slice} W[r,k] * s[k,c] (LDS broadcast) ----
        float acc[CPG] = {0.f,0.f,0.f,0.f,0.f,0.f,0.f,0.f};
        #pragma unroll
        for (int h = 0; h < 2; ++h) {
            #pragma unroll
            for (int kk = 0; kk < 16; ++kk) {
                #pragma unroll
                for (int c = 0; c < 4; ++c) {
                    const int ci = h * 4 + c;
                    const float4 s4 = *(const float4*)&sLDS[ci * N_ + k0 + kk * 4];
                    acc[ci] = fmaf(w[kk].x, s4.x, acc[ci]);
                    acc[ci] = fmaf(w[kk].y, s4.y, acc[ci]);
                    acc[ci] = fmaf(w[kk].z, s4.z, acc[ci]);
                    acc[ci] = fmaf(w[kk].w, s4.w, acc[ci]);
                }
            }
        }
        // split-K partials -> LDS (two b128 per thread)
        *(float4*)&pw[(wv * 64 + ln) * CPG + 0] = make_float4(acc[0], acc[1], acc[2], acc[3]);
        *(float4*)&pw[(wv * 64 + ln) * CPG + 4] = make_float4(acc[4], acc[5], acc[6], acc[7]);
        // park prefetched values in LDS
        if (tid < 512)                        rnLDS[tid] = pf;
        else if (tid < 512 + NI_ * CPG)       uLDS[tid - 512] = pf;
        else if (tid < 512 + 2 * NI_ * CPG)   inoLDS[tid - 512 - NI_ * CPG] = pf;
        __syncthreads();

        // ---- reduce + pointwise + publish + output projection ----
        float* sbn = sbuf + (size_t)((t + 1) & 1) * SBT + (size_t)g * SBG;
        if (tid < 512) {
            const int c = tid >> 6, r = tid & 63, n = r0 + r;
            float hs = 0.f;
            #pragma unroll
            for (int w2 = 0; w2 < 16; ++w2) hs += pw[(w2 * 64 + r) * CPG + c];
            #pragma unroll
            for (int q = 0; q < NI_; ++q)
                hs = fmaf(Winp[n * NI_ + q],
                          fmaf(NS_, inoLDS[q * CPG + c], uLDS[q * CPG + c]), hs);
            const float s_old = sLDS[c * N_ + n];
            const float rhs   = -s_old + fmaxf(0.f, hs) + NS_ * rnLDS[r * CPG + c]
                                - GAMMA_ * s_old * s_old * s_old;
            const float snew  = fmaf(ALPHA_, rhs, s_old);
            st_sys(&sbn[c * N_ + n], snew);     // coalesced along n within wave
            #pragma unroll
            for (int o = 0; o < NO_; ++o) {
                float p = Wout[o * N_ + n] * snew;
                #pragma unroll
                for (int off = 32; off; off >>= 1) p += __shfl_down(p, off, 64);
                if (r == 0)
                    atomicAdd(&out[(size_t)o * (T_ * B_) + (t + 1) * B_ + col0 + c], p);
            }
        }
        asm volatile("s_waitcnt vmcnt(0)" ::: "memory");  // s-stores at coherence point
        __syncthreads();

        // ---- group barrier + stage s_{t+1} ----
        target += NRB;
        if (t < T_ - 2) {
            if (tid == 0) {
                __hip_atomic_fetch_add(&arrive[g], 1u, __ATOMIC_RELAXED, __HIP_MEMORY_SCOPE_AGENT);
                while (__hip_atomic_load(&arrive[g], __ATOMIC_RELAXED, __HIP_MEMORY_SCOPE_AGENT) < target)
                    __builtin_amdgcn_s_sleep(1);
            }
            __syncthreads();
            #pragma unroll
            for (int i = 0; i < 2; ++i) {                 // 8 KB/thread-group, wide+coalesced
                const int off = i * 4096 + tid * 4;       // dword offset, 16B aligned
                const float4 v = ld_sys((const float4*)&sbn[off]);
                *(float4*)&sLDS[off] = v;
            }
            __syncthreads();
        }
    }
}

extern "C" void kernel_launch(void* const* d_in, const int* in_sizes, int n_in,
                              void* d_out, int out_size, void* d_ws, size_t ws_size,
                              hipStream_t stream) {
    const float* u    = (const float*)d_in[0];
    const float* rn   = (const float*)d_in[1];
    const float* ino  = (const float*)d_in[2];
    const float* Wrec = (const float*)d_in[3];
    const float* Winp = (const float*)d_in[4];
    const float* Wout = (const float*)d_in[5];
    const float* yin  = (const float*)d_in[6];
    float* out = (float*)d_out;

    unsigned int* arrive = (unsigned int*)d_ws;           // 16 counters
    float* sbuf = (float*)((char*)d_ws + 256);            // 1 MB ping-pong

    hipMemsetAsync(d_ws, 0, 256, stream);
    hipMemsetAsync(d_out, 0, (size_t)out_size * sizeof(float), stream);

    void* args[] = {(void*)&u, (void*)&rn, (void*)&ino, (void*)&Wrec, (void*)&Winp,
                    (void*)&Wout, (void*)&yin, (void*)&out, (void*)&arrive, (void*)&sbuf};
    hipLaunchCooperativeKernel((void*)rnn_kernel, dim3(256), dim3(1024), args, 0, stream);
}

// Round 4
// 7299.467 us; speedup vs baseline: 3.7167x; 2.7868x over previous
//
#include <hip/hip_runtime.h>

typedef float f32x4 __attribute__((ext_vector_type(4)));

#define N_  1024
#define T_  512
#define B_  128
#define NI_ 6
#define NO_ 2
#define NS_ 0.13416407864998738f   // sqrt(2/alpha)*sigma = sqrt(20)*0.03
#define ALPHA_ 0.1f
#define GAMMA_ 0.1f

#define NG   16     // column groups (8 cols each)
#define CPG  8      // cols per group
#define RPB  64     // rows per block
#define NRB  16     // row-blocks per group
#define SBG  (CPG * N_)          // floats per group slice (8192)
#define SBT  (NG * SBG)          // floats per time buffer

// pin the 64 W VGPRs so the compiler cannot rematerialize the loads in-loop
#define PIN_W(W) asm volatile("" \
    : "+v"(W[0]), "+v"(W[1]), "+v"(W[2]),  "+v"(W[3]),  "+v"(W[4]),  "+v"(W[5]),  "+v"(W[6]),  "+v"(W[7]), \
      "+v"(W[8]), "+v"(W[9]), "+v"(W[10]), "+v"(W[11]), "+v"(W[12]), "+v"(W[13]), "+v"(W[14]), "+v"(W[15]))

__device__ __forceinline__ void st_sys(float* p, float v) {
    asm volatile("global_store_dword %0, %1, off sc0 sc1" :: "v"(p), "v"(v) : "memory");
}

// 256 blocks = 16 col-groups x 16 row-blocks; 1024 threads = 16 waves.
// W_rec slice (64 rows x 1024) lives in VGPRs: wave w holds k-slice [64w,64w+64),
// lane = row; 16 x f32x4 per thread, loaded once, reused for all 511 steps.
// __launch_bounds__(1024,4): VGPR cap 128 -> W fits; 1 block/CU -> even placement.
__global__ __launch_bounds__(1024, 4) void rnn_kernel(
    const float* __restrict__ u,      // (NI, T, B)
    const float* __restrict__ rn,     // (N, T, B)
    const float* __restrict__ ino,    // (NI, T, B)
    const float* __restrict__ Wrec,   // (N, N)
    const float* __restrict__ Winp,   // (N, NI)
    const float* __restrict__ Wout,   // (NO, N)
    const float* __restrict__ yinit,  // (N,)
    float* __restrict__ out,          // (NO, T, B) pre-zeroed
    unsigned int* __restrict__ arrive,// NG counters (zeroed)
    float* __restrict__ sbuf)         // 2 * SBT floats ping-pong
{
    __shared__ float sLDS[CPG * N_];        // s_t slice [c][k]        32 KB
    __shared__ float pw[CPG * N_];          // partials [c][w*64+r]    32 KB
    __shared__ float rnLDS[RPB * 9];        // padded stride 9         2.25 KB
    __shared__ float uLDS[NI_ * CPG];
    __shared__ float inoLDS[NI_ * CPG];
    __shared__ float WinpL[RPB * 7];        // padded stride 7
    __shared__ float WoutL[NO_ * RPB];

    const int bid  = blockIdx.x;
    const int g    = bid >> 4;            // col group
    const int R    = bid & 15;            // row block
    const int col0 = g * CPG;
    const int r0   = R * RPB;
    const int tid  = threadIdx.x;
    const int wv   = tid >> 6;            // k-slice (wave)
    const int ln   = tid & 63;            // row within block
    const int k0   = wv * 64;

    // ---- persistent W fragment: W[r0+ln][k0 .. k0+63] ----
    f32x4 w[16];
    {
        const float* wrow = Wrec + (size_t)(r0 + ln) * N_ + k0;
        #pragma unroll
        for (int kk = 0; kk < 16; ++kk)
            w[kk] = *(const f32x4*)&wrow[kk * 4];
    }
    PIN_W(w);

    // ---- stage small weights + s0 into LDS ----
    if (tid < RPB * NI_) {                 // Winp rows r0..r0+63, padded stride 7
        const int r = tid / NI_, q = tid % NI_;
        WinpL[r * 7 + q] = Winp[(r0 + r) * NI_ + q];
    }
    if (tid < NO_ * RPB)
        WoutL[tid] = Wout[(tid >> 6) * N_ + r0 + (tid & 63)];
    #pragma unroll
    for (int i = 0; i < 8; ++i) {
        const int idx = i * 1024 + tid;    // [c][k] flat
        sLDS[idx] = yinit[idx & 1023];
    }
    __syncthreads();

    // ---- prologue: out[:,0,:] ----
    if (tid < 512) {
        const int c = tid >> 6, r = tid & 63;
        const float v = sLDS[r0 + r];      // == yinit[r0+r]
        #pragma unroll
        for (int o = 0; o < NO_; ++o) {
            float p = WoutL[o * RPB + r] * v;
            #pragma unroll
            for (int off = 32; off; off >>= 1) p += __shfl_down(p, off, 64);
            if (r == 0) atomicAdd(&out[(size_t)o * (T_ * B_) + col0 + c], p);
        }
    }

    unsigned int target = 0;

    for (int t = 0; t < T_ - 1; ++t) {
        PIN_W(w);
        // ---- prefetch pointwise inputs (overlap with GEMM) ----
        float pf = 0.f;
        if (tid < 512) {                        // rn: 64 rows x 8 cols
            const int pn = tid >> 3, pc = tid & 7;
            pf = rn[(size_t)(r0 + pn) * (T_ * B_) + t * B_ + col0 + pc];
        } else if (tid < 512 + 2 * NI_ * CPG) { // u, ino: 96 values
            const int j = tid - 512;
            const int q = (j >> 3) % NI_, pc = j & 7;
            const float* src = (j < NI_ * CPG) ? u : ino;
            pf = src[q * (T_ * B_) + t * B_ + col0 + pc];
        }

        // ---- GEMM: acc[c] = sum_k W[r,k] * s[k,c]; s via wave-uniform LDS bcast
        float acc[CPG] = {0.f,0.f,0.f,0.f,0.f,0.f,0.f,0.f};
        #pragma unroll
        for (int kk = 0; kk < 16; ++kk) {
            #pragma unroll
            for (int c = 0; c < CPG; ++c) {
                const f32x4 s4 = *(const f32x4*)&sLDS[c * N_ + k0 + kk * 4];
                acc[c] = fmaf(w[kk][0], s4[0], acc[c]);
                acc[c] = fmaf(w[kk][1], s4[1], acc[c]);
                acc[c] = fmaf(w[kk][2], s4[2], acc[c]);
                acc[c] = fmaf(w[kk][3], s4[3], acc[c]);
            }
        }
        // partials: [c][tid] -> stride-1 lanes, conflict-free
        #pragma unroll
        for (int c = 0; c < CPG; ++c)
            pw[c * N_ + tid] = acc[c];
        // park prefetched values
        if (tid < 512)                        rnLDS[(tid >> 3) * 9 + (tid & 7)] = pf;
        else if (tid < 512 + NI_ * CPG)       uLDS[tid - 512] = pf;
        else if (tid < 512 + 2 * NI_ * CPG)   inoLDS[tid - 512 - NI_ * CPG] = pf;
        __syncthreads();

        // ---- reduce 16-way split-K + pointwise + publish + out projection ----
        float* sbn = sbuf + (size_t)((t + 1) & 1) * SBT + (size_t)g * SBG;
        if (tid < 512) {
            const int c = tid >> 6, r = tid & 63, n = r0 + r;
            float hs = 0.f;
            #pragma unroll
            for (int w2 = 0; w2 < 16; ++w2) hs += pw[c * N_ + w2 * 64 + r];
            #pragma unroll
            for (int q = 0; q < NI_; ++q)
                hs = fmaf(WinpL[r * 7 + q],
                          fmaf(NS_, inoLDS[q * CPG + c], uLDS[q * CPG + c]), hs);
            const float s_old = sLDS[c * N_ + n];
            const float rhs   = -s_old + fmaxf(0.f, hs) + NS_ * rnLDS[r * 9 + c]
                                - GAMMA_ * s_old * s_old * s_old;
            const float snew  = fmaf(ALPHA_, rhs, s_old);
            st_sys(&sbn[c * N_ + n], snew);     // coalesced along n within wave
            #pragma unroll
            for (int o = 0; o < NO_; ++o) {
                float p = WoutL[o * RPB + r] * snew;
                #pragma unroll
                for (int off = 32; off; off >>= 1) p += __shfl_down(p, off, 64);
                if (r == 0)
                    atomicAdd(&out[(size_t)o * (T_ * B_) + (t + 1) * B_ + col0 + c], p);
            }
        }
        asm volatile("s_waitcnt vmcnt(0)" ::: "memory");  // s-stores at coherence point
        __syncthreads();

        // ---- group barrier (16 blocks) + stage s_{t+1} ----
        target += NRB;
        if (t < T_ - 2) {
            if (tid == 0) {
                __hip_atomic_fetch_add(&arrive[g], 1u, __ATOMIC_RELAXED, __HIP_MEMORY_SCOPE_AGENT);
                while (__hip_atomic_load(&arrive[g], __ATOMIC_RELAXED, __HIP_MEMORY_SCOPE_AGENT) < target)
                    __builtin_amdgcn_s_sleep(1);
            }
            __syncthreads();
            {   // both loads in flight, single wait
                const float* src0 = sbn + tid * 4;
                const float* src1 = sbn + 4096 + tid * 4;
                f32x4 a, b;
                asm volatile("global_load_dwordx4 %0, %2, off sc0 sc1\n\t"
                             "global_load_dwordx4 %1, %3, off sc0 sc1\n\t"
                             "s_waitcnt vmcnt(0)"
                             : "=v"(a), "=v"(b) : "v"(src0), "v"(src1) : "memory");
                *(f32x4*)&sLDS[tid * 4] = a;
                *(f32x4*)&sLDS[4096 + tid * 4] = b;
            }
            __syncthreads();
        }
    }
}

extern "C" void kernel_launch(void* const* d_in, const int* in_sizes, int n_in,
                              void* d_out, int out_size, void* d_ws, size_t ws_size,
                              hipStream_t stream) {
    const float* u    = (const float*)d_in[0];
    const float* rn   = (const float*)d_in[1];
    const float* ino  = (const float*)d_in[2];
    const float* Wrec = (const float*)d_in[3];
    const float* Winp = (const float*)d_in[4];
    const float* Wout = (const float*)d_in[5];
    const float* yin  = (const float*)d_in[6];
    float* out = (float*)d_out;

    unsigned int* arrive = (unsigned int*)d_ws;           // 16 counters
    float* sbuf = (float*)((char*)d_ws + 256);            // 1 MB ping-pong

    hipMemsetAsync(d_ws, 0, 256, stream);
    hipMemsetAsync(d_out, 0, (size_t)out_size * sizeof(float), stream);

    void* args[] = {(void*)&u, (void*)&rn, (void*)&ino, (void*)&Wrec, (void*)&Winp,
                    (void*)&Wout, (void*)&yin, (void*)&out, (void*)&arrive, (void*)&sbuf};
    hipLaunchCooperativeKernel((void*)rnn_kernel, dim3(256), dim3(1024), args, 0, stream);
}